// Round 3
// baseline (470.349 us; speedup 1.0000x reference)
//
#include <hip/hip_runtime.h>
#include <hip/hip_bf16.h>

#define Bn 2
#define Sn 4096
#define Dn 512
#define Hn 8
#define DKn 64

typedef __attribute__((ext_vector_type(8))) short bf16x8;
typedef __attribute__((ext_vector_type(4))) float f32x4;
typedef __attribute__((ext_vector_type(4))) _Float16 f16x4;
typedef __attribute__((ext_vector_type(8))) _Float16 f16x8;
typedef __attribute__((ext_vector_type(2))) _Float16 f16x2;
typedef __attribute__((ext_vector_type(8))) unsigned short us8;
typedef __attribute__((ext_vector_type(4))) unsigned short us4;

__device__ __forceinline__ unsigned short f2bf(float f) {
  unsigned u = __builtin_bit_cast(unsigned, f);
  u += 0x7fffu + ((u >> 16) & 1u);   // RNE; inputs finite
  return (unsigned short)(u >> 16);
}

// gfx950 packed fp32->bf16 (RNE). lo -> D[15:0], hi -> D[31:16].
__device__ __forceinline__ unsigned cvtpk_bf16(float lo, float hi) {
  unsigned r;
  asm("v_cvt_pk_bf16_f32 %0, %1, %2" : "=v"(r) : "v"(lo), "v"(hi));
  return r;
}

// -------------------------------------------------------------------- prep
// blockIdx.x < 256 : weights -> bf16 W^T tiles (Q-scale folded into w_q).
// blockIdx.x >= 256: mask 32:1 bit-pack, transposed pm[b][kvw][q], grid-stride.
__global__ __launch_bounds__(256) void prep_k(
    const int* __restrict__ mask, unsigned int* __restrict__ pm,
    const float* __restrict__ wq, const float* __restrict__ wk,
    const float* __restrict__ wv, const float* __restrict__ wo,
    unsigned short* __restrict__ wt) {
  const int t = threadIdx.x;
  if (blockIdx.x < 256) {
    __shared__ unsigned short ls[64][68];
    int bid = blockIdx.x;
    int z = bid >> 6, x = bid & 7, y = (bid >> 3) & 7;
    const float* W = z == 0 ? wq : z == 1 ? wk : z == 2 ? wv : wo;
    // fold softmax scale (1/sqrt(dk) * log2e) into W_q so GEMM epilogue is a
    // plain cvt and flash_k's exp2 needs no extra multiply.
    const float wsc = (z == 0) ? 0.18033688011112042f : 1.0f;
    int k0 = x * 64, n0 = y * 64;
    for (int j = 0; j < 4; ++j) {
      int i = t + j * 256;
      int r = i >> 4, c4 = (i & 15) << 2;
      float4 f = *(const float4*)&W[(size_t)(k0 + r) * 512 + n0 + c4];
      ls[c4 + 0][r] = f2bf(f.x * wsc);
      ls[c4 + 1][r] = f2bf(f.y * wsc);
      ls[c4 + 2][r] = f2bf(f.z * wsc);
      ls[c4 + 3][r] = f2bf(f.w * wsc);
    }
    __syncthreads();
    unsigned short* out = wt + (size_t)z * 512 * 512;
    for (int j = 0; j < 4; ++j) {
      int i = t + j * 256;
      int r = i >> 4, c4 = (i & 15) << 2;
      us4 v = {ls[r][c4], ls[r][c4 + 1], ls[r][c4 + 2], ls[r][c4 + 3]};
      *(us4*)&out[(size_t)(n0 + r) * 512 + k0 + c4] = v;
    }
  } else {
    size_t idx = (size_t)(blockIdx.x - 256) * 256 + t;
    for (int it = 0; it < 8; ++it, idx += 4194304) {
      int m = mask[idx];
      unsigned long long bal = __ballot(m != 0);
      if ((t & 63) == 0) {
        int q = (int)((idx >> 12) & 4095);
        int b = (int)(idx >> 24);
        int kvw = (int)((idx >> 5) & 127);
        pm[((size_t)b * 128 + kvw) * 4096 + q] = (unsigned)bal;
        pm[((size_t)b * 128 + kvw + 1) * 4096 + q] = (unsigned)(bal >> 32);
      }
    }
  }
}

// ------------------------------------------------------------------- GEMM
// C[8192,512] = A @ W[512,512]. BM=MT*64, BN=128, BK=64, 4 waves, LDS
// double-buffered, ONE barrier per k-tile. HEADS: A is fp32 (cvt fused in
// staging via v_cvt_pk_bf16_f32); z<2 -> bf16 heads, z==2 -> f16 V^T
// pos-permuted via in-LDS transpose. !HEADS: A bf16, fp32 linear out.
template <int MT, bool HEADS>
__global__ __launch_bounds__(256, 2) void gemm_k(
    const float* __restrict__ aq, const float* __restrict__ ak,
    const float* __restrict__ av, const unsigned short* __restrict__ abf,
    const unsigned short* __restrict__ wt, unsigned short* __restrict__ oh,
    unsigned short* __restrict__ vtg, float* __restrict__ olin) {
  __shared__ unsigned short smem[MT * 8192 + 16384];  // As[2] | Bs[2]
  const int z = blockIdx.z;
  const float* A32 = HEADS ? (z == 0 ? aq : z == 1 ? ak : av) : nullptr;
  const unsigned short* Wt = wt + (size_t)z * 512 * 512;
  const int m0 = blockIdx.x * (MT * 64), n0 = blockIdx.y * 128;
  const int t = threadIdx.x, w = t >> 6, l = t & 63;
  const int quad = l >> 4, c = l & 15;

  f32x4 acc[MT][8] = {};
  us8 apre[MT * 2], bpre[4];

  auto ldA = [&](int j, int kk) -> us8 {
    int i = t + j * 256, r = i >> 3, u = i & 7;
    if constexpr (HEADS) {
      const float* s = &A32[(size_t)(m0 + r) * 512 + kk + (u << 3)];
      float4 f0 = *(const float4*)s;
      float4 f1 = *(const float4*)(s + 4);
      uint4 p;
      p.x = cvtpk_bf16(f0.x, f0.y);
      p.y = cvtpk_bf16(f0.z, f0.w);
      p.z = cvtpk_bf16(f1.x, f1.y);
      p.w = cvtpk_bf16(f1.z, f1.w);
      return __builtin_bit_cast(us8, p);
    } else {
      return *(const us8*)&abf[(size_t)(m0 + r) * 512 + kk + (u << 3)];
    }
  };

#pragma unroll
  for (int j = 0; j < MT * 2; ++j) apre[j] = ldA(j, 0);
#pragma unroll
  for (int j = 0; j < 4; ++j) {
    int i = t + j * 256, r = i >> 3, u = i & 7;
    bpre[j] = *(const us8*)&Wt[(size_t)(n0 + r) * 512 + (u << 3)];
  }
#pragma unroll
  for (int j = 0; j < MT * 2; ++j) {   // stage buf 0
    int i = t + j * 256, r = i >> 3, u = i & 7;
    *(us8*)&smem[r * 64 + ((u ^ (r & 7)) << 3)] = apre[j];
  }
#pragma unroll
  for (int j = 0; j < 4; ++j) {
    int i = t + j * 256, r = i >> 3, u = i & 7;
    *(us8*)&smem[MT * 8192 + r * 64 + ((u ^ (r & 7)) << 3)] = bpre[j];
  }

  for (int k0 = 0; k0 < 512; k0 += 64) {
    const int cur = (k0 >> 6) & 1;
    const unsigned short* AsC = &smem[cur * (MT * 4096)];
    const unsigned short* BsC = &smem[MT * 8192 + cur * 8192];
    __syncthreads();
    const bool nxt = k0 + 64 < 512;
    if (nxt) {
#pragma unroll
      for (int j = 0; j < MT * 2; ++j) apre[j] = ldA(j, k0 + 64);
#pragma unroll
      for (int j = 0; j < 4; ++j) {
        int i = t + j * 256, r = i >> 3, u = i & 7;
        bpre[j] = *(const us8*)&Wt[(size_t)(n0 + r) * 512 + k0 + 64 + (u << 3)];
      }
    }

#pragma unroll
    for (int kc = 0; kc < 2; ++kc) {
      bf16x8 aA[MT], bB[8];
      int u = kc * 4 + quad;
#pragma unroll
      for (int mt = 0; mt < MT; ++mt) {
        int row = w * (MT * 16) + mt * 16 + c;
        aA[mt] = *(const bf16x8*)&AsC[row * 64 + ((u ^ (c & 7)) << 3)];
      }
#pragma unroll
      for (int nt = 0; nt < 8; ++nt) {
        int row = nt * 16 + c;
        bB[nt] = *(const bf16x8*)&BsC[row * 64 + ((u ^ (c & 7)) << 3)];
      }
      __builtin_amdgcn_s_setprio(1);
#pragma unroll
      for (int mt = 0; mt < MT; ++mt)
#pragma unroll
        for (int nt = 0; nt < 8; ++nt)
          acc[mt][nt] = __builtin_amdgcn_mfma_f32_16x16x32_bf16(
              aA[mt], bB[nt], acc[mt][nt], 0, 0, 0);
      __builtin_amdgcn_s_setprio(0);
    }

    if (nxt) {
      unsigned short* AsN = &smem[(cur ^ 1) * (MT * 4096)];
      unsigned short* BsN = &smem[MT * 8192 + (cur ^ 1) * 8192];
#pragma unroll
      for (int j = 0; j < MT * 2; ++j) {
        int i = t + j * 256, r = i >> 3, u = i & 7;
        *(us8*)&AsN[r * 64 + ((u ^ (r & 7)) << 3)] = apre[j];
      }
#pragma unroll
      for (int j = 0; j < 4; ++j) {
        int i = t + j * 256, r = i >> 3, u = i & 7;
        *(us8*)&BsN[r * 64 + ((u ^ (r & 7)) << 3)] = bpre[j];
      }
    }
  }

  if constexpr (HEADS) {
    if (z == 2) {
      // ---- V^T epilogue via LDS transpose (pitch 152 shorts) ----
      __syncthreads();
#pragma unroll
      for (int mt = 0; mt < MT; ++mt) {
        int mb = w * (MT * 16) + mt * 16 + (quad << 2);
        int ml = (mb & 64) | (((mb >> 5) & 1) << 5) | (((mb >> 2) & 3) << 3) |
                 (((mb >> 4) & 1) << 2);                  // pos-permuted coord
#pragma unroll
        for (int nt = 0; nt < 8; ++nt) {
          int nl = nt * 16 + c;
          us4 pk;
#pragma unroll
          for (int r = 0; r < 4; ++r)
            pk[r] = __builtin_bit_cast(unsigned short, (_Float16)acc[mt][nt][r]);
          *(us4*)&smem[nl * 152 + ml] = pk;
        }
      }
      __syncthreads();
      const int bb = m0 >> 12, sb = m0 & 4095;
#pragma unroll
      for (int j = 0; j < MT * 4; ++j) {
        int i = t + j * 256;
        int nl = i >> 4, mc = (i & 15) << 3;
        us8 vv = *(const us8*)&smem[nl * 152 + mc];
        int n = n0 + nl, hh = n >> 6, dk = n & 63;
        *(us8*)&vtg[((size_t)(bb * Hn + hh) * DKn + dk) * Sn + sb + mc] = vv;
      }
    } else {
#pragma unroll
      for (int mt = 0; mt < MT; ++mt)
#pragma unroll
        for (int nt = 0; nt < 8; ++nt) {
          int m = m0 + w * (MT * 16) + mt * 16 + (quad << 2);
          int n = n0 + nt * 16 + c;
          int b = m >> 12, s = m & 4095, hh = n >> 6, dk = n & 63;
          unsigned short* dst = &oh[(size_t)z * (Bn * Hn * Sn * DKn) +
                                    ((size_t)(b * Hn + hh) * Sn + s) * DKn + dk];
          unsigned pk0 = cvtpk_bf16(acc[mt][nt][0], acc[mt][nt][1]);
          unsigned pk1 = cvtpk_bf16(acc[mt][nt][2], acc[mt][nt][3]);
          dst[0] = (unsigned short)pk0;
          dst[DKn] = (unsigned short)(pk0 >> 16);
          dst[2 * DKn] = (unsigned short)pk1;
          dst[3 * DKn] = (unsigned short)(pk1 >> 16);
        }
    }
  } else {
#pragma unroll
    for (int mt = 0; mt < MT; ++mt)
#pragma unroll
      for (int nt = 0; nt < 8; ++nt)
#pragma unroll
        for (int r = 0; r < 4; ++r) {
          int m = m0 + w * (MT * 16) + mt * 16 + (quad << 2) + r;
          int n = n0 + nt * 16 + c;
          olin[(size_t)m * 512 + n] = acc[mt][nt][r];
        }
  }
}

// ------------------------------------------------------------- flash attn
// 512 thr = 2 kv-groups x 4 waves x 32 q. Static-max softmax; P in regs;
// row-sum l via MFMA ones-trick (lane-local, no shuffles); PV f16 K=32.
// Mask applied as AND on packed f16 P via conflict-free 16-entry LDS table.
// Grid flattened; h = bid&7 so each head's K/V pins to one XCD's L2 (T1).
// Prefetch issued IMMEDIATELY post-barrier (before QK^T) — moving it later
// exposed HBM latency at the double-buffer write (R2: 91->131 us regression).
__global__ __launch_bounds__(512, 4) void flash_k(
    const unsigned short* __restrict__ Qh, const unsigned short* __restrict__ Kh,
    const unsigned short* __restrict__ VtG, const unsigned int* __restrict__ pmt,
    unsigned short* __restrict__ attn) {
  __shared__ unsigned short Ks[2][2][64 * 64];   // [group][parity][kv][d]
  __shared__ unsigned short Vts[2][2][64 * 64];  // [group][parity][dk][pos]
  __shared__ unsigned int Mw[2][2][256];
  __shared__ unsigned long long MskT[16];        // nibble -> f16x4 AND mask

  const int bid = blockIdx.x;
  const int h = bid & 7;                 // XCD = id%8 -> head h clusters on XCD h
  const int b = (bid >> 3) & 1;
  const int q0 = (bid >> 4) * 128;
  const int t = threadIdx.x;
  const int g = t >> 8, tg = t & 255;
  const int w = (t >> 6) & 3, l = t & 63;
  const int quad = l >> 4, c = l & 15;
  const size_t hb = (size_t)(b * Hn + h) * Sn * DKn;
  const unsigned short* Qg = Qh + hb;

  if (t < 16) {
    unsigned lo = ((t & 1) ? 0xFFFFu : 0u) | ((t & 2) ? 0xFFFF0000u : 0u);
    unsigned hi = ((t & 4) ? 0xFFFFu : 0u) | ((t & 8) ? 0xFFFF0000u : 0u);
    MskT[t] = ((unsigned long long)hi << 32) | lo;
  }

  bf16x8 bQ[2][2];
#pragma unroll
  for (int qf = 0; qf < 2; ++qf) {
    int qrow = q0 + w * 32 + qf * 16 + c;
#pragma unroll
    for (int kc = 0; kc < 2; ++kc)
      bQ[qf][kc] = *(const bf16x8*)&Qg[(size_t)qrow * 64 + kc * 32 + quad * 8];
  }

  f32x4 oacc[2][4] = {};
  f32x4 oaccl[2] = {};                 // rowsum frag: reg r <-> q = quad*4+r
  f16x8 vone8;
#pragma unroll
  for (int i = 0; i < 8; ++i) vone8[i] = (_Float16)1.0f;

  const int sr = tg >> 3, su = tg & 7;
  const int off0 = sr * 64 + ((su ^ (sr & 7)) << 3);
  const int off1 = (sr + 32) * 64 + ((su ^ (sr & 7)) << 3);

  // stepped staging pointers (tile stride: K rows +128, V cols +128, mask +4 rows)
  const unsigned short* kp0 = Kh + hb + ((size_t)(g * 64 + sr)) * 64 + (su << 3);
  const unsigned short* kp1 = kp0 + 32 * 64;
  const unsigned short* vp0 = VtG + hb + (size_t)sr * Sn + g * 64 + (su << 3);
  const unsigned short* vp1 = VtG + hb + (size_t)(sr + 32) * Sn + g * 64 + (su << 3);
  const unsigned int* mp =
      pmt + ((size_t)b * 128 + g * 2 + (tg >> 7)) * 4096 + q0 + (tg & 127);

  us8 kpre[2], vpre[2];
  unsigned mpre;
  kpre[0] = *(const us8*)kp0;
  kpre[1] = *(const us8*)kp1;
  vpre[0] = *(const us8*)vp0;
  vpre[1] = *(const us8*)vp1;
  mpre = *mp;
  *(us8*)&Ks[g][0][off0] = kpre[0];
  *(us8*)&Ks[g][0][off1] = kpre[1];
  *(us8*)&Vts[g][0][off0] = vpre[0];
  *(us8*)&Vts[g][0][off1] = vpre[1];
  Mw[g][0][tg] = mpre;

  for (int it = 0; it < 32; ++it) {
    const int cur = it & 1;
    __syncthreads();
    const bool nxt = it + 1 < 32;
    // ---- issue next-tile global prefetch FIRST (max latency-hiding window)
    if (nxt) {
      kp0 += 8192; kp1 += 8192; vp0 += 128; vp1 += 128; mp += 16384;
      kpre[0] = *(const us8*)kp0;
      kpre[1] = *(const us8*)kp1;
      vpre[0] = *(const us8*)vp0;
      vpre[1] = *(const us8*)vp1;
      mpre = *mp;
    }

    // ---- S^T = K . Q^T (high prio: keep matrix pipe fed)
    f32x4 sacc[2][4] = {};
    __builtin_amdgcn_s_setprio(1);
#pragma unroll
    for (int kc = 0; kc < 2; ++kc) {
      int u = kc * 4 + quad;
#pragma unroll
      for (int kvt = 0; kvt < 4; ++kvt) {
        int row = kvt * 16 + c;
        bf16x8 aK = *(const bf16x8*)&Ks[g][cur][row * 64 + ((u ^ (c & 7)) << 3)];
#pragma unroll
        for (int qf = 0; qf < 2; ++qf)
          sacc[qf][kvt] = __builtin_amdgcn_mfma_f32_16x16x32_bf16(
              aK, bQ[qf][kc], sacc[qf][kvt], 0, 0, 0);
      }
    }
    __builtin_amdgcn_s_setprio(0);

    // ---- unconditional exp2 -> packed f16, mask via LDS AND-table
    f16x8 ph[2][2];   // [qf][half-of-64kv]
#pragma unroll
    for (int qf = 0; qf < 2; ++qf) {
      int qloc = w * 32 + qf * 16 + c;
      unsigned mv0 = Mw[g][cur][qloc] >> (quad << 2);
      unsigned mv1 = Mw[g][cur][128 + qloc] >> (quad << 2);
#pragma unroll
      for (int half = 0; half < 2; ++half) {
        unsigned wd = half ? mv1 : mv0;
        uint4 ww;
#pragma unroll
        for (int kvh = 0; kvh < 2; ++kvh) {
          const f32x4 s4 = sacc[qf][half * 2 + kvh];
          unsigned long long mk = MskT[(wd >> (kvh << 4)) & 15u];
          unsigned a = __builtin_bit_cast(
              unsigned, __builtin_amdgcn_cvt_pkrtz(
                            __builtin_amdgcn_exp2f(s4[0]),
                            __builtin_amdgcn_exp2f(s4[1])));
          unsigned bpk = __builtin_bit_cast(
              unsigned, __builtin_amdgcn_cvt_pkrtz(
                            __builtin_amdgcn_exp2f(s4[2]),
                            __builtin_amdgcn_exp2f(s4[3])));
          (&ww.x)[kvh * 2] = a & (unsigned)mk;
          (&ww.x)[kvh * 2 + 1] = bpk & (unsigned)(mk >> 32);
        }
        ph[qf][half] = __builtin_bit_cast(f16x8, ww);
      }
    }

    // ---- O += P.V ; l += P.1 (ones-MFMA), high prio
    __builtin_amdgcn_s_setprio(1);
#pragma unroll
    for (int half = 0; half < 2; ++half) {
      int u2 = half * 4 + quad;
#pragma unroll
      for (int dkt = 0; dkt < 4; ++dkt) {
        int dk = dkt * 16 + c;
        f16x8 bV = __builtin_bit_cast(
            f16x8, *(const us8*)&Vts[g][cur][dk * 64 + ((u2 ^ (c & 7)) << 3)]);
#pragma unroll
        for (int qf = 0; qf < 2; ++qf)
          oacc[qf][dkt] = __builtin_amdgcn_mfma_f32_16x16x32_f16(
              ph[qf][half], bV, oacc[qf][dkt], 0, 0, 0);
      }
#pragma unroll
      for (int qf = 0; qf < 2; ++qf)
        oaccl[qf] = __builtin_amdgcn_mfma_f32_16x16x32_f16(
            ph[qf][half], vone8, oaccl[qf], 0, 0, 0);
    }
    __builtin_amdgcn_s_setprio(0);

    if (nxt) {
      const int nb = cur ^ 1;
      *(us8*)&Ks[g][nb][off0] = kpre[0];
      *(us8*)&Ks[g][nb][off1] = kpre[1];
      *(us8*)&Vts[g][nb][off0] = vpre[0];
      *(us8*)&Vts[g][nb][off1] = vpre[1];
      Mw[g][nb][tg] = mpre;
    }
  }

  // ---- combine groups (plain sums), normalize, store (group 0)
  __syncthreads();
  float* fsum = (float*)&Ks[0][0][0];          // [qf][dkt][w][l] f32x4 = 32 KB
  float* flsum = (float*)&Vts[0][0][0];        // [qf][w][l] f32x4 = 8 KB
  if (g == 1) {
#pragma unroll
    for (int qf = 0; qf < 2; ++qf) {
#pragma unroll
      for (int dkt = 0; dkt < 4; ++dkt)
        *(f32x4*)&fsum[(((qf * 4 + dkt) * 4 + w) * 64 + l) * 4] = oacc[qf][dkt];
      *(f32x4*)&flsum[((qf * 4 + w) * 64 + l) * 4] = oaccl[qf];
    }
  }
  __syncthreads();
  if (g == 0) {
#pragma unroll
    for (int qf = 0; qf < 2; ++qf) {
      f32x4 l1 = *(const f32x4*)&flsum[((qf * 4 + w) * 64 + l) * 4];
#pragma unroll
      for (int r = 0; r < 4; ++r) oaccl[qf][r] += l1[r];
#pragma unroll
      for (int dkt = 0; dkt < 4; ++dkt) {
        f32x4 o1 = *(const f32x4*)&fsum[(((qf * 4 + dkt) * 4 + w) * 64 + l) * 4];
#pragma unroll
        for (int r = 0; r < 4; ++r) oacc[qf][dkt][r] += o1[r];
      }
    }
#pragma unroll
    for (int qf = 0; qf < 2; ++qf)
#pragma unroll
      for (int r = 0; r < 4; ++r) {
        float invr = 1.0f / oaccl[qf][r];
        unsigned short* dst =
            &attn[((size_t)(b * Sn + q0 + w * 32 + qf * 16 + (quad << 2) + r)) * Dn +
                  h * 64 + c];
#pragma unroll
        for (int dkt = 0; dkt < 4; ++dkt)
          dst[dkt * 16] = f2bf(oacc[qf][dkt][r] * invr);
      }
  }
}

// ------------------------------------------------------------------ launch
extern "C" void kernel_launch(void* const* d_in, const int* in_sizes, int n_in,
                              void* d_out, int out_size, void* d_ws,
                              size_t ws_size, hipStream_t stream) {
  const float* q = (const float*)d_in[0];
  const float* k = (const float*)d_in[1];
  const float* v = (const float*)d_in[2];
  const int* mask = (const int*)d_in[3];
  const float* wq = (const float*)d_in[4];
  const float* wk = (const float*)d_in[5];
  const float* wv = (const float*)d_in[6];
  const float* wo = (const float*)d_in[7];
  float* out = (float*)d_out;

  char* ws = (char*)d_ws;
  const size_t headN = (size_t)Bn * Hn * Sn * DKn;        // 4,194,304 elems
  const size_t tensB = headN * 2;                          // 8 MB
  unsigned short* attn = (unsigned short*)ws;
  size_t off = 3 * tensB;
  unsigned short* qkv = (unsigned short*)(ws + off);       // Q,K heads + V^T
  off += 3 * tensB;
  unsigned short* wt = (unsigned short*)(ws + off);        // 2 MB
  off += 4ull * 512 * 512 * 2;
  unsigned int* pm = (unsigned int*)(ws + off);            // 4 MB transposed

  prep_k<<<16640, 256, 0, stream>>>(mask, pm, wq, wk, wv, wo, wt);
  gemm_k<2, true><<<dim3(64, 4, 3), 256, 0, stream>>>(
      q, k, v, nullptr, wt, qkv, qkv + 2 * headN, nullptr);
  flash_k<<<dim3(512), 512, 0, stream>>>(qkv, qkv + headN,
                                         qkv + 2 * headN, pm, attn);
  gemm_k<1, false><<<dim3(128, 4, 1), 256, 0, stream>>>(
      nullptr, nullptr, nullptr, attn, wt + 3ull * 512 * 512, nullptr, nullptr,
      out);
}

// Round 4
// 362.412 us; speedup vs baseline: 1.2978x; 1.2978x over previous
//
#include <hip/hip_runtime.h>
#include <hip/hip_bf16.h>

#define Bn 2
#define Sn 4096
#define Dn 512
#define Hn 8
#define DKn 64

typedef __attribute__((ext_vector_type(8))) short bf16x8;
typedef __attribute__((ext_vector_type(4))) float f32x4;
typedef __attribute__((ext_vector_type(4))) _Float16 f16x4;
typedef __attribute__((ext_vector_type(8))) _Float16 f16x8;
typedef __attribute__((ext_vector_type(2))) _Float16 f16x2;
typedef __attribute__((ext_vector_type(8))) unsigned short us8;
typedef __attribute__((ext_vector_type(4))) unsigned short us4;

__device__ __forceinline__ unsigned short f2bf(float f) {
  unsigned u = __builtin_bit_cast(unsigned, f);
  u += 0x7fffu + ((u >> 16) & 1u);   // RNE; inputs finite
  return (unsigned short)(u >> 16);
}

// gfx950 packed fp32->bf16 (RNE). lo -> D[15:0], hi -> D[31:16].
__device__ __forceinline__ unsigned cvtpk_bf16(float lo, float hi) {
  unsigned r;
  asm("v_cvt_pk_bf16_f32 %0, %1, %2" : "=v"(r) : "v"(lo), "v"(hi));
  return r;
}

// -------------------------------------------------------------------- prep
// blockIdx.x < 256 : weights -> bf16 W^T tiles (Q-scale folded into w_q).
// blockIdx.x >= 256: mask 32:1 bit-pack, transposed pm[b][kvw][q], grid-stride.
__global__ __launch_bounds__(256) void prep_k(
    const int* __restrict__ mask, unsigned int* __restrict__ pm,
    const float* __restrict__ wq, const float* __restrict__ wk,
    const float* __restrict__ wv, const float* __restrict__ wo,
    unsigned short* __restrict__ wt) {
  const int t = threadIdx.x;
  if (blockIdx.x < 256) {
    __shared__ unsigned short ls[64][68];
    int bid = blockIdx.x;
    int z = bid >> 6, x = bid & 7, y = (bid >> 3) & 7;
    const float* W = z == 0 ? wq : z == 1 ? wk : z == 2 ? wv : wo;
    // fold softmax scale (1/sqrt(dk) * log2e) into W_q so GEMM epilogue is a
    // plain cvt and flash_k's exp2 needs no extra multiply.
    const float wsc = (z == 0) ? 0.18033688011112042f : 1.0f;
    int k0 = x * 64, n0 = y * 64;
    for (int j = 0; j < 4; ++j) {
      int i = t + j * 256;
      int r = i >> 4, c4 = (i & 15) << 2;
      float4 f = *(const float4*)&W[(size_t)(k0 + r) * 512 + n0 + c4];
      ls[c4 + 0][r] = f2bf(f.x * wsc);
      ls[c4 + 1][r] = f2bf(f.y * wsc);
      ls[c4 + 2][r] = f2bf(f.z * wsc);
      ls[c4 + 3][r] = f2bf(f.w * wsc);
    }
    __syncthreads();
    unsigned short* out = wt + (size_t)z * 512 * 512;
    for (int j = 0; j < 4; ++j) {
      int i = t + j * 256;
      int r = i >> 4, c4 = (i & 15) << 2;
      us4 v = {ls[r][c4], ls[r][c4 + 1], ls[r][c4 + 2], ls[r][c4 + 3]};
      *(us4*)&out[(size_t)(n0 + r) * 512 + k0 + c4] = v;
    }
  } else {
    size_t idx = (size_t)(blockIdx.x - 256) * 256 + t;
    for (int it = 0; it < 8; ++it, idx += 4194304) {
      int m = mask[idx];
      unsigned long long bal = __ballot(m != 0);
      if ((t & 63) == 0) {
        int q = (int)((idx >> 12) & 4095);
        int b = (int)(idx >> 24);
        int kvw = (int)((idx >> 5) & 127);
        pm[((size_t)b * 128 + kvw) * 4096 + q] = (unsigned)bal;
        pm[((size_t)b * 128 + kvw + 1) * 4096 + q] = (unsigned)(bal >> 32);
      }
    }
  }
}

// ------------------------------------------------------------------- GEMM
// C[8192,512] = A @ W[512,512]. BM=MT*64, BN=128, BK=64, 4 waves, LDS
// double-buffered, ONE barrier per k-tile. HEADS: A is fp32 (cvt fused in
// staging via v_cvt_pk_bf16_f32); z<2 -> bf16 heads, z==2 -> f16 V^T
// pos-permuted via in-LDS transpose. !HEADS: A bf16, fp32 linear out.
template <int MT, bool HEADS>
__global__ __launch_bounds__(256, 2) void gemm_k(
    const float* __restrict__ aq, const float* __restrict__ ak,
    const float* __restrict__ av, const unsigned short* __restrict__ abf,
    const unsigned short* __restrict__ wt, unsigned short* __restrict__ oh,
    unsigned short* __restrict__ vtg, float* __restrict__ olin) {
  __shared__ unsigned short smem[MT * 8192 + 16384];  // As[2] | Bs[2]
  const int z = blockIdx.z;
  const float* A32 = HEADS ? (z == 0 ? aq : z == 1 ? ak : av) : nullptr;
  const unsigned short* Wt = wt + (size_t)z * 512 * 512;
  const int m0 = blockIdx.x * (MT * 64), n0 = blockIdx.y * 128;
  const int t = threadIdx.x, w = t >> 6, l = t & 63;
  const int quad = l >> 4, c = l & 15;

  f32x4 acc[MT][8] = {};
  us8 apre[MT * 2], bpre[4];

  auto ldA = [&](int j, int kk) -> us8 {
    int i = t + j * 256, r = i >> 3, u = i & 7;
    if constexpr (HEADS) {
      const float* s = &A32[(size_t)(m0 + r) * 512 + kk + (u << 3)];
      float4 f0 = *(const float4*)s;
      float4 f1 = *(const float4*)(s + 4);
      uint4 p;
      p.x = cvtpk_bf16(f0.x, f0.y);
      p.y = cvtpk_bf16(f0.z, f0.w);
      p.z = cvtpk_bf16(f1.x, f1.y);
      p.w = cvtpk_bf16(f1.z, f1.w);
      return __builtin_bit_cast(us8, p);
    } else {
      return *(const us8*)&abf[(size_t)(m0 + r) * 512 + kk + (u << 3)];
    }
  };

#pragma unroll
  for (int j = 0; j < MT * 2; ++j) apre[j] = ldA(j, 0);
#pragma unroll
  for (int j = 0; j < 4; ++j) {
    int i = t + j * 256, r = i >> 3, u = i & 7;
    bpre[j] = *(const us8*)&Wt[(size_t)(n0 + r) * 512 + (u << 3)];
  }
#pragma unroll
  for (int j = 0; j < MT * 2; ++j) {   // stage buf 0
    int i = t + j * 256, r = i >> 3, u = i & 7;
    *(us8*)&smem[r * 64 + ((u ^ (r & 7)) << 3)] = apre[j];
  }
#pragma unroll
  for (int j = 0; j < 4; ++j) {
    int i = t + j * 256, r = i >> 3, u = i & 7;
    *(us8*)&smem[MT * 8192 + r * 64 + ((u ^ (r & 7)) << 3)] = bpre[j];
  }

  for (int k0 = 0; k0 < 512; k0 += 64) {
    const int cur = (k0 >> 6) & 1;
    const unsigned short* AsC = &smem[cur * (MT * 4096)];
    const unsigned short* BsC = &smem[MT * 8192 + cur * 8192];
    __syncthreads();
    const bool nxt = k0 + 64 < 512;
    if (nxt) {
#pragma unroll
      for (int j = 0; j < MT * 2; ++j) apre[j] = ldA(j, k0 + 64);
#pragma unroll
      for (int j = 0; j < 4; ++j) {
        int i = t + j * 256, r = i >> 3, u = i & 7;
        bpre[j] = *(const us8*)&Wt[(size_t)(n0 + r) * 512 + k0 + 64 + (u << 3)];
      }
    }

#pragma unroll
    for (int kc = 0; kc < 2; ++kc) {
      bf16x8 aA[MT], bB[8];
      int u = kc * 4 + quad;
#pragma unroll
      for (int mt = 0; mt < MT; ++mt) {
        int row = w * (MT * 16) + mt * 16 + c;
        aA[mt] = *(const bf16x8*)&AsC[row * 64 + ((u ^ (c & 7)) << 3)];
      }
#pragma unroll
      for (int nt = 0; nt < 8; ++nt) {
        int row = nt * 16 + c;
        bB[nt] = *(const bf16x8*)&BsC[row * 64 + ((u ^ (c & 7)) << 3)];
      }
      __builtin_amdgcn_s_setprio(1);
#pragma unroll
      for (int mt = 0; mt < MT; ++mt)
#pragma unroll
        for (int nt = 0; nt < 8; ++nt)
          acc[mt][nt] = __builtin_amdgcn_mfma_f32_16x16x32_bf16(
              aA[mt], bB[nt], acc[mt][nt], 0, 0, 0);
      __builtin_amdgcn_s_setprio(0);
    }

    if (nxt) {
      unsigned short* AsN = &smem[(cur ^ 1) * (MT * 4096)];
      unsigned short* BsN = &smem[MT * 8192 + (cur ^ 1) * 8192];
#pragma unroll
      for (int j = 0; j < MT * 2; ++j) {
        int i = t + j * 256, r = i >> 3, u = i & 7;
        *(us8*)&AsN[r * 64 + ((u ^ (r & 7)) << 3)] = apre[j];
      }
#pragma unroll
      for (int j = 0; j < 4; ++j) {
        int i = t + j * 256, r = i >> 3, u = i & 7;
        *(us8*)&BsN[r * 64 + ((u ^ (r & 7)) << 3)] = bpre[j];
      }
    }
  }

  if constexpr (HEADS) {
    if (z == 2) {
      // ---- V^T epilogue via LDS transpose (pitch 152 shorts) ----
      __syncthreads();
#pragma unroll
      for (int mt = 0; mt < MT; ++mt) {
        int mb = w * (MT * 16) + mt * 16 + (quad << 2);
        int ml = (mb & 64) | (((mb >> 5) & 1) << 5) | (((mb >> 2) & 3) << 3) |
                 (((mb >> 4) & 1) << 2);                  // pos-permuted coord
#pragma unroll
        for (int nt = 0; nt < 8; ++nt) {
          int nl = nt * 16 + c;
          us4 pk;
#pragma unroll
          for (int r = 0; r < 4; ++r)
            pk[r] = __builtin_bit_cast(unsigned short, (_Float16)acc[mt][nt][r]);
          *(us4*)&smem[nl * 152 + ml] = pk;
        }
      }
      __syncthreads();
      const int bb = m0 >> 12, sb = m0 & 4095;
#pragma unroll
      for (int j = 0; j < MT * 4; ++j) {
        int i = t + j * 256;
        int nl = i >> 4, mc = (i & 15) << 3;
        us8 vv = *(const us8*)&smem[nl * 152 + mc];
        int n = n0 + nl, hh = n >> 6, dk = n & 63;
        *(us8*)&vtg[((size_t)(bb * Hn + hh) * DKn + dk) * Sn + sb + mc] = vv;
      }
    } else {
#pragma unroll
      for (int mt = 0; mt < MT; ++mt)
#pragma unroll
        for (int nt = 0; nt < 8; ++nt) {
          int m = m0 + w * (MT * 16) + mt * 16 + (quad << 2);
          int n = n0 + nt * 16 + c;
          int b = m >> 12, s = m & 4095, hh = n >> 6, dk = n & 63;
          unsigned short* dst = &oh[(size_t)z * (Bn * Hn * Sn * DKn) +
                                    ((size_t)(b * Hn + hh) * Sn + s) * DKn + dk];
          unsigned pk0 = cvtpk_bf16(acc[mt][nt][0], acc[mt][nt][1]);
          unsigned pk1 = cvtpk_bf16(acc[mt][nt][2], acc[mt][nt][3]);
          dst[0] = (unsigned short)pk0;
          dst[DKn] = (unsigned short)(pk0 >> 16);
          dst[2 * DKn] = (unsigned short)pk1;
          dst[3 * DKn] = (unsigned short)(pk1 >> 16);
        }
    }
  } else {
#pragma unroll
    for (int mt = 0; mt < MT; ++mt)
#pragma unroll
      for (int nt = 0; nt < 8; ++nt)
#pragma unroll
        for (int r = 0; r < 4; ++r) {
          int m = m0 + w * (MT * 16) + mt * 16 + (quad << 2) + r;
          int n = n0 + nt * 16 + c;
          olin[(size_t)m * 512 + n] = acc[mt][nt][r];
        }
  }
}

// ------------------------------------------------------------- flash attn
// 512 thr = 2 kv-groups x 4 waves x 32 q. Static-max softmax; P in regs;
// row-sum l via MFMA ones-trick (lane-local, no shuffles); PV f16 K=32.
// Mask applied as AND on packed f16 P via conflict-free 16-entry LDS table.
// Grid flattened; h = bid&7 so each head's K/V pins to one XCD's L2 (T1).
// NOTE (R2/R3 lessons): prefetch MUST be issued immediately post-barrier
// (late issue exposes HBM latency at the dbuf write: 91->131 us), and NO
// s_setprio here — its scheduler fences force the prefetch regs live across
// the MFMA regions -> per-iteration scratch spill storm (WRITE 16->525 MB,
// 222 us). setprio is fine in gemm_k, fatal here.
__global__ __launch_bounds__(512, 4) void flash_k(
    const unsigned short* __restrict__ Qh, const unsigned short* __restrict__ Kh,
    const unsigned short* __restrict__ VtG, const unsigned int* __restrict__ pmt,
    unsigned short* __restrict__ attn) {
  __shared__ unsigned short Ks[2][2][64 * 64];   // [group][parity][kv][d]
  __shared__ unsigned short Vts[2][2][64 * 64];  // [group][parity][dk][pos]
  __shared__ unsigned int Mw[2][2][256];
  __shared__ unsigned long long MskT[16];        // nibble -> f16x4 AND mask

  const int bid = blockIdx.x;
  const int h = bid & 7;                 // XCD = id%8 -> head h clusters on XCD h
  const int b = (bid >> 3) & 1;
  const int q0 = (bid >> 4) * 128;
  const int t = threadIdx.x;
  const int g = t >> 8, tg = t & 255;
  const int w = (t >> 6) & 3, l = t & 63;
  const int quad = l >> 4, c = l & 15;
  const size_t hb = (size_t)(b * Hn + h) * Sn * DKn;
  const unsigned short* Qg = Qh + hb;

  if (t < 16) {
    unsigned lo = ((t & 1) ? 0xFFFFu : 0u) | ((t & 2) ? 0xFFFF0000u : 0u);
    unsigned hi = ((t & 4) ? 0xFFFFu : 0u) | ((t & 8) ? 0xFFFF0000u : 0u);
    MskT[t] = ((unsigned long long)hi << 32) | lo;
  }

  bf16x8 bQ[2][2];
#pragma unroll
  for (int qf = 0; qf < 2; ++qf) {
    int qrow = q0 + w * 32 + qf * 16 + c;
#pragma unroll
    for (int kc = 0; kc < 2; ++kc)
      bQ[qf][kc] = *(const bf16x8*)&Qg[(size_t)qrow * 64 + kc * 32 + quad * 8];
  }

  f32x4 oacc[2][4] = {};
  f32x4 oaccl[2] = {};                 // rowsum frag: reg r <-> q = quad*4+r
  f16x8 vone8;
#pragma unroll
  for (int i = 0; i < 8; ++i) vone8[i] = (_Float16)1.0f;

  const int sr = tg >> 3, su = tg & 7;
  const int off0 = sr * 64 + ((su ^ (sr & 7)) << 3);
  const int off1 = (sr + 32) * 64 + ((su ^ (sr & 7)) << 3);

  // stepped staging pointers (tile stride: K rows +128, V cols +128, mask +4 rows)
  const unsigned short* kp0 = Kh + hb + ((size_t)(g * 64 + sr)) * 64 + (su << 3);
  const unsigned short* kp1 = kp0 + 32 * 64;
  const unsigned short* vp0 = VtG + hb + (size_t)sr * Sn + g * 64 + (su << 3);
  const unsigned short* vp1 = VtG + hb + (size_t)(sr + 32) * Sn + g * 64 + (su << 3);
  const unsigned int* mp =
      pmt + ((size_t)b * 128 + g * 2 + (tg >> 7)) * 4096 + q0 + (tg & 127);

  us8 kpre[2], vpre[2];
  unsigned mpre;
  kpre[0] = *(const us8*)kp0;
  kpre[1] = *(const us8*)kp1;
  vpre[0] = *(const us8*)vp0;
  vpre[1] = *(const us8*)vp1;
  mpre = *mp;
  *(us8*)&Ks[g][0][off0] = kpre[0];
  *(us8*)&Ks[g][0][off1] = kpre[1];
  *(us8*)&Vts[g][0][off0] = vpre[0];
  *(us8*)&Vts[g][0][off1] = vpre[1];
  Mw[g][0][tg] = mpre;

  for (int it = 0; it < 32; ++it) {
    const int cur = it & 1;
    __syncthreads();
    const bool nxt = it + 1 < 32;
    if (nxt) {
      kp0 += 8192; kp1 += 8192; vp0 += 128; vp1 += 128; mp += 16384;
      kpre[0] = *(const us8*)kp0;
      kpre[1] = *(const us8*)kp1;
      vpre[0] = *(const us8*)vp0;
      vpre[1] = *(const us8*)vp1;
      mpre = *mp;
    }

    // ---- S^T = K . Q^T
    f32x4 sacc[2][4] = {};
#pragma unroll
    for (int kc = 0; kc < 2; ++kc) {
      int u = kc * 4 + quad;
#pragma unroll
      for (int kvt = 0; kvt < 4; ++kvt) {
        int row = kvt * 16 + c;
        bf16x8 aK = *(const bf16x8*)&Ks[g][cur][row * 64 + ((u ^ (c & 7)) << 3)];
#pragma unroll
        for (int qf = 0; qf < 2; ++qf)
          sacc[qf][kvt] = __builtin_amdgcn_mfma_f32_16x16x32_bf16(
              aK, bQ[qf][kc], sacc[qf][kvt], 0, 0, 0);
      }
    }

    // ---- unconditional exp2 -> packed f16, mask via LDS AND-table
    f16x8 ph[2][2];   // [qf][half-of-64kv]
#pragma unroll
    for (int qf = 0; qf < 2; ++qf) {
      int qloc = w * 32 + qf * 16 + c;
      unsigned mv0 = Mw[g][cur][qloc] >> (quad << 2);
      unsigned mv1 = Mw[g][cur][128 + qloc] >> (quad << 2);
#pragma unroll
      for (int half = 0; half < 2; ++half) {
        unsigned wd = half ? mv1 : mv0;
        uint4 ww;
#pragma unroll
        for (int kvh = 0; kvh < 2; ++kvh) {
          const f32x4 s4 = sacc[qf][half * 2 + kvh];
          unsigned long long mk = MskT[(wd >> (kvh << 4)) & 15u];
          unsigned a = __builtin_bit_cast(
              unsigned, __builtin_amdgcn_cvt_pkrtz(
                            __builtin_amdgcn_exp2f(s4[0]),
                            __builtin_amdgcn_exp2f(s4[1])));
          unsigned bpk = __builtin_bit_cast(
              unsigned, __builtin_amdgcn_cvt_pkrtz(
                            __builtin_amdgcn_exp2f(s4[2]),
                            __builtin_amdgcn_exp2f(s4[3])));
          (&ww.x)[kvh * 2] = a & (unsigned)mk;
          (&ww.x)[kvh * 2 + 1] = bpk & (unsigned)(mk >> 32);
        }
        ph[qf][half] = __builtin_bit_cast(f16x8, ww);
      }
    }

    // ---- O += P.V ; l += P.1 (ones-MFMA)
#pragma unroll
    for (int half = 0; half < 2; ++half) {
      int u2 = half * 4 + quad;
#pragma unroll
      for (int dkt = 0; dkt < 4; ++dkt) {
        int dk = dkt * 16 + c;
        f16x8 bV = __builtin_bit_cast(
            f16x8, *(const us8*)&Vts[g][cur][dk * 64 + ((u2 ^ (c & 7)) << 3)]);
#pragma unroll
        for (int qf = 0; qf < 2; ++qf)
          oacc[qf][dkt] = __builtin_amdgcn_mfma_f32_16x16x32_f16(
              ph[qf][half], bV, oacc[qf][dkt], 0, 0, 0);
      }
#pragma unroll
      for (int qf = 0; qf < 2; ++qf)
        oaccl[qf] = __builtin_amdgcn_mfma_f32_16x16x32_f16(
            ph[qf][half], vone8, oaccl[qf], 0, 0, 0);
    }

    if (nxt) {
      const int nb = cur ^ 1;
      *(us8*)&Ks[g][nb][off0] = kpre[0];
      *(us8*)&Ks[g][nb][off1] = kpre[1];
      *(us8*)&Vts[g][nb][off0] = vpre[0];
      *(us8*)&Vts[g][nb][off1] = vpre[1];
      Mw[g][nb][tg] = mpre;
    }
  }

  // ---- combine groups (plain sums), normalize, store (group 0)
  __syncthreads();
  float* fsum = (float*)&Ks[0][0][0];          // [qf][dkt][w][l] f32x4 = 32 KB
  float* flsum = (float*)&Vts[0][0][0];        // [qf][w][l] f32x4 = 8 KB
  if (g == 1) {
#pragma unroll
    for (int qf = 0; qf < 2; ++qf) {
#pragma unroll
      for (int dkt = 0; dkt < 4; ++dkt)
        *(f32x4*)&fsum[(((qf * 4 + dkt) * 4 + w) * 64 + l) * 4] = oacc[qf][dkt];
      *(f32x4*)&flsum[((qf * 4 + w) * 64 + l) * 4] = oaccl[qf];
    }
  }
  __syncthreads();
  if (g == 0) {
#pragma unroll
    for (int qf = 0; qf < 2; ++qf) {
      f32x4 l1 = *(const f32x4*)&flsum[((qf * 4 + w) * 64 + l) * 4];
#pragma unroll
      for (int r = 0; r < 4; ++r) oaccl[qf][r] += l1[r];
#pragma unroll
      for (int dkt = 0; dkt < 4; ++dkt) {
        f32x4 o1 = *(const f32x4*)&fsum[(((qf * 4 + dkt) * 4 + w) * 64 + l) * 4];
#pragma unroll
        for (int r = 0; r < 4; ++r) oacc[qf][dkt][r] += o1[r];
      }
    }
#pragma unroll
    for (int qf = 0; qf < 2; ++qf)
#pragma unroll
      for (int r = 0; r < 4; ++r) {
        float invr = 1.0f / oaccl[qf][r];
        unsigned short* dst =
            &attn[((size_t)(b * Sn + q0 + w * 32 + qf * 16 + (quad << 2) + r)) * Dn +
                  h * 64 + c];
#pragma unroll
        for (int dkt = 0; dkt < 4; ++dkt)
          dst[dkt * 16] = f2bf(oacc[qf][dkt][r] * invr);
      }
  }
}

// ------------------------------------------------------------------ launch
extern "C" void kernel_launch(void* const* d_in, const int* in_sizes, int n_in,
                              void* d_out, int out_size, void* d_ws,
                              size_t ws_size, hipStream_t stream) {
  const float* q = (const float*)d_in[0];
  const float* k = (const float*)d_in[1];
  const float* v = (const float*)d_in[2];
  const int* mask = (const int*)d_in[3];
  const float* wq = (const float*)d_in[4];
  const float* wk = (const float*)d_in[5];
  const float* wv = (const float*)d_in[6];
  const float* wo = (const float*)d_in[7];
  float* out = (float*)d_out;

  char* ws = (char*)d_ws;
  const size_t headN = (size_t)Bn * Hn * Sn * DKn;        // 4,194,304 elems
  const size_t tensB = headN * 2;                          // 8 MB
  unsigned short* attn = (unsigned short*)ws;
  size_t off = 3 * tensB;
  unsigned short* qkv = (unsigned short*)(ws + off);       // Q,K heads + V^T
  off += 3 * tensB;
  unsigned short* wt = (unsigned short*)(ws + off);        // 2 MB
  off += 4ull * 512 * 512 * 2;
  unsigned int* pm = (unsigned int*)(ws + off);            // 4 MB transposed

  prep_k<<<16640, 256, 0, stream>>>(mask, pm, wq, wk, wv, wo, wt);
  gemm_k<2, true><<<dim3(64, 4, 3), 256, 0, stream>>>(
      q, k, v, nullptr, wt, qkv, qkv + 2 * headN, nullptr);
  flash_k<<<dim3(512), 512, 0, stream>>>(qkv, qkv + headN,
                                         qkv + 2 * headN, pm, attn);
  gemm_k<1, false><<<dim3(128, 4, 1), 256, 0, stream>>>(
      nullptr, nullptr, nullptr, attn, wt + 3ull * 512 * 512, nullptr, nullptr,
      out);
}

// Round 7
// 346.671 us; speedup vs baseline: 1.3568x; 1.0454x over previous
//
#include <hip/hip_runtime.h>
#include <hip/hip_bf16.h>

#define Bn 2
#define Sn 4096
#define Dn 512
#define Hn 8
#define DKn 64

typedef __attribute__((ext_vector_type(8))) short bf16x8;
typedef __attribute__((ext_vector_type(4))) float f32x4;
typedef __attribute__((ext_vector_type(4))) _Float16 f16x4;
typedef __attribute__((ext_vector_type(8))) _Float16 f16x8;
typedef __attribute__((ext_vector_type(2))) _Float16 f16x2;
typedef __attribute__((ext_vector_type(8))) unsigned short us8;
typedef __attribute__((ext_vector_type(4))) unsigned short us4;

__device__ __forceinline__ unsigned short f2bf(float f) {
  unsigned u = __builtin_bit_cast(unsigned, f);
  u += 0x7fffu + ((u >> 16) & 1u);   // RNE; inputs finite
  return (unsigned short)(u >> 16);
}

// gfx950 packed fp32->bf16 (RNE). lo -> D[15:0], hi -> D[31:16].
__device__ __forceinline__ unsigned cvtpk_bf16(float lo, float hi) {
  unsigned r;
  asm("v_cvt_pk_bf16_f32 %0, %1, %2" : "=v"(r) : "v"(lo), "v"(hi));
  return r;
}

// bit j of byte -> bit 4j (for interleaved mask repack; pm stays bit-identical)
__device__ __forceinline__ unsigned spread4(unsigned x) {
  x = (x | (x << 12)) & 0x000F000Fu;
  x = (x | (x << 6)) & 0x03030303u;
  x = (x | (x << 3)) & 0x11111111u;
  return x;
}

// -------------------------------------------------------------------- prep
// blockIdx.x < 256 : weights -> bf16 W^T tiles (Q-scale folded into w_q).
// blockIdx.x >= 256: mask 32:1 bit-pack, transposed pm[b][kvw][q]. int4
// vectorized (1KB/wave/instr): 4x ballot + spread4 interleave; pm output is
// bit-identical to the scalar path (R4 and earlier).
__global__ __launch_bounds__(256) void prep_k(
    const int* __restrict__ mask, unsigned int* __restrict__ pm,
    const float* __restrict__ wq, const float* __restrict__ wk,
    const float* __restrict__ wv, const float* __restrict__ wo,
    unsigned short* __restrict__ wt) {
  const int t = threadIdx.x;
  if (blockIdx.x < 256) {
    __shared__ unsigned short ls[64][68];
    int bid = blockIdx.x;
    int z = bid >> 6, x = bid & 7, y = (bid >> 3) & 7;
    const float* W = z == 0 ? wq : z == 1 ? wk : z == 2 ? wv : wo;
    // fold softmax scale (1/sqrt(dk) * log2e) into W_q so GEMM epilogue is a
    // plain cvt and flash_k's exp2 needs no extra multiply.
    const float wsc = (z == 0) ? 0.18033688011112042f : 1.0f;
    int k0 = x * 64, n0 = y * 64;
    for (int j = 0; j < 4; ++j) {
      int i = t + j * 256;
      int r = i >> 4, c4 = (i & 15) << 2;
      float4 f = *(const float4*)&W[(size_t)(k0 + r) * 512 + n0 + c4];
      ls[c4 + 0][r] = f2bf(f.x * wsc);
      ls[c4 + 1][r] = f2bf(f.y * wsc);
      ls[c4 + 2][r] = f2bf(f.z * wsc);
      ls[c4 + 3][r] = f2bf(f.w * wsc);
    }
    __syncthreads();
    unsigned short* out = wt + (size_t)z * 512 * 512;
    for (int j = 0; j < 4; ++j) {
      int i = t + j * 256;
      int r = i >> 4, c4 = (i & 15) << 2;
      us4 v = {ls[r][c4], ls[r][c4 + 1], ls[r][c4 + 2], ls[r][c4 + 3]};
      *(us4*)&out[(size_t)(n0 + r) * 512 + k0 + c4] = v;
    }
  } else {
    // 4096 mask blocks x 256 thr x 8 it x int4 = 2*4096*4096 elements
    size_t gt = (size_t)(blockIdx.x - 256) * 256 + t;   // int4 index
    for (int it = 0; it < 8; ++it, gt += 1048576) {
      size_t e0 = gt * 4;                                // element index
      int4 mv = *(const int4*)&mask[e0];
      unsigned long long bl0 = __ballot(mv.x != 0);
      unsigned long long bl1 = __ballot(mv.y != 0);
      unsigned long long bl2 = __ballot(mv.z != 0);
      unsigned long long bl3 = __ballot(mv.w != 0);
      if ((t & 63) < 8) {
        int wd = t & 7;
        unsigned word = spread4((unsigned)(bl0 >> (wd * 8)) & 0xFFu) |
                        (spread4((unsigned)(bl1 >> (wd * 8)) & 0xFFu) << 1) |
                        (spread4((unsigned)(bl2 >> (wd * 8)) & 0xFFu) << 2) |
                        (spread4((unsigned)(bl3 >> (wd * 8)) & 0xFFu) << 3);
        size_t eb = e0 & ~(size_t)255;     // wave-base element (256-aligned)
        int qq = (int)((eb >> 12) & 4095);
        int bb = (int)(eb >> 24);
        int kvw = (int)((eb >> 5) & 127) + wd;
        pm[((size_t)bb * 128 + kvw) * 4096 + qq] = word;
      }
    }
  }
}

// ------------------------------------------------------------------- GEMM
// C[8192,512] = A @ W[512,512]. BM=MT*64, BN=128, BK=64, 4 waves, LDS
// double-buffered, ONE barrier per k-tile. HEADS: A is fp32 (cvt fused in
// staging via v_cvt_pk_bf16_f32); z<2 -> bf16 heads, z==2 -> f16 V^T
// pos-permuted via in-LDS transpose. !HEADS: A bf16, fp32 linear out.
template <int MT, bool HEADS>
__global__ __launch_bounds__(256, 2) void gemm_k(
    const float* __restrict__ aq, const float* __restrict__ ak,
    const float* __restrict__ av, const unsigned short* __restrict__ abf,
    const unsigned short* __restrict__ wt, unsigned short* __restrict__ oh,
    unsigned short* __restrict__ vtg, float* __restrict__ olin) {
  __shared__ unsigned short smem[MT * 8192 + 16384];  // As[2] | Bs[2]
  const int z = blockIdx.z;
  const float* A32 = HEADS ? (z == 0 ? aq : z == 1 ? ak : av) : nullptr;
  const unsigned short* Wt = wt + (size_t)z * 512 * 512;
  const int m0 = blockIdx.x * (MT * 64), n0 = blockIdx.y * 128;
  const int t = threadIdx.x, w = t >> 6, l = t & 63;
  const int quad = l >> 4, c = l & 15;

  f32x4 acc[MT][8] = {};
  us8 apre[MT * 2], bpre[4];

  auto ldA = [&](int j, int kk) -> us8 {
    int i = t + j * 256, r = i >> 3, u = i & 7;
    if constexpr (HEADS) {
      const float* s = &A32[(size_t)(m0 + r) * 512 + kk + (u << 3)];
      float4 f0 = *(const float4*)s;
      float4 f1 = *(const float4*)(s + 4);
      uint4 p;
      p.x = cvtpk_bf16(f0.x, f0.y);
      p.y = cvtpk_bf16(f0.z, f0.w);
      p.z = cvtpk_bf16(f1.x, f1.y);
      p.w = cvtpk_bf16(f1.z, f1.w);
      return __builtin_bit_cast(us8, p);
    } else {
      return *(const us8*)&abf[(size_t)(m0 + r) * 512 + kk + (u << 3)];
    }
  };

#pragma unroll
  for (int j = 0; j < MT * 2; ++j) apre[j] = ldA(j, 0);
#pragma unroll
  for (int j = 0; j < 4; ++j) {
    int i = t + j * 256, r = i >> 3, u = i & 7;
    bpre[j] = *(const us8*)&Wt[(size_t)(n0 + r) * 512 + (u << 3)];
  }
#pragma unroll
  for (int j = 0; j < MT * 2; ++j) {   // stage buf 0
    int i = t + j * 256, r = i >> 3, u = i & 7;
    *(us8*)&smem[r * 64 + ((u ^ (r & 7)) << 3)] = apre[j];
  }
#pragma unroll
  for (int j = 0; j < 4; ++j) {
    int i = t + j * 256, r = i >> 3, u = i & 7;
    *(us8*)&smem[MT * 8192 + r * 64 + ((u ^ (r & 7)) << 3)] = bpre[j];
  }

  for (int k0 = 0; k0 < 512; k0 += 64) {
    const int cur = (k0 >> 6) & 1;
    const unsigned short* AsC = &smem[cur * (MT * 4096)];
    const unsigned short* BsC = &smem[MT * 8192 + cur * 8192];
    __syncthreads();
    const bool nxt = k0 + 64 < 512;
    if (nxt) {
#pragma unroll
      for (int j = 0; j < MT * 2; ++j) apre[j] = ldA(j, k0 + 64);
#pragma unroll
      for (int j = 0; j < 4; ++j) {
        int i = t + j * 256, r = i >> 3, u = i & 7;
        bpre[j] = *(const us8*)&Wt[(size_t)(n0 + r) * 512 + k0 + 64 + (u << 3)];
      }
    }

#pragma unroll
    for (int kc = 0; kc < 2; ++kc) {
      bf16x8 aA[MT], bB[8];
      int u = kc * 4 + quad;
#pragma unroll
      for (int mt = 0; mt < MT; ++mt) {
        int row = w * (MT * 16) + mt * 16 + c;
        aA[mt] = *(const bf16x8*)&AsC[row * 64 + ((u ^ (c & 7)) << 3)];
      }
#pragma unroll
      for (int nt = 0; nt < 8; ++nt) {
        int row = nt * 16 + c;
        bB[nt] = *(const bf16x8*)&BsC[row * 64 + ((u ^ (c & 7)) << 3)];
      }
      __builtin_amdgcn_s_setprio(1);
#pragma unroll
      for (int mt = 0; mt < MT; ++mt)
#pragma unroll
        for (int nt = 0; nt < 8; ++nt)
          acc[mt][nt] = __builtin_amdgcn_mfma_f32_16x16x32_bf16(
              aA[mt], bB[nt], acc[mt][nt], 0, 0, 0);
      __builtin_amdgcn_s_setprio(0);
    }

    if (nxt) {
      unsigned short* AsN = &smem[(cur ^ 1) * (MT * 4096)];
      unsigned short* BsN = &smem[MT * 8192 + (cur ^ 1) * 8192];
#pragma unroll
      for (int j = 0; j < MT * 2; ++j) {
        int i = t + j * 256, r = i >> 3, u = i & 7;
        *(us8*)&AsN[r * 64 + ((u ^ (r & 7)) << 3)] = apre[j];
      }
#pragma unroll
      for (int j = 0; j < 4; ++j) {
        int i = t + j * 256, r = i >> 3, u = i & 7;
        *(us8*)&BsN[r * 64 + ((u ^ (r & 7)) << 3)] = bpre[j];
      }
    }
  }

  if constexpr (HEADS) {
    if (z == 2) {
      // ---- V^T epilogue via LDS transpose (pitch 152 shorts) ----
      __syncthreads();
#pragma unroll
      for (int mt = 0; mt < MT; ++mt) {
        int mb = w * (MT * 16) + mt * 16 + (quad << 2);
        int ml = (mb & 64) | (((mb >> 5) & 1) << 5) | (((mb >> 2) & 3) << 3) |
                 (((mb >> 4) & 1) << 2);                  // pos-permuted coord
#pragma unroll
        for (int nt = 0; nt < 8; ++nt) {
          int nl = nt * 16 + c;
          us4 pk;
#pragma unroll
          for (int r = 0; r < 4; ++r)
            pk[r] = __builtin_bit_cast(unsigned short, (_Float16)acc[mt][nt][r]);
          *(us4*)&smem[nl * 152 + ml] = pk;
        }
      }
      __syncthreads();
      const int bb = m0 >> 12, sb = m0 & 4095;
#pragma unroll
      for (int j = 0; j < MT * 4; ++j) {
        int i = t + j * 256;
        int nl = i >> 4, mc = (i & 15) << 3;
        us8 vv = *(const us8*)&smem[nl * 152 + mc];
        int n = n0 + nl, hh = n >> 6, dk = n & 63;
        *(us8*)&vtg[((size_t)(bb * Hn + hh) * DKn + dk) * Sn + sb + mc] = vv;
      }
    } else {
#pragma unroll
      for (int mt = 0; mt < MT; ++mt)
#pragma unroll
        for (int nt = 0; nt < 8; ++nt) {
          int m = m0 + w * (MT * 16) + mt * 16 + (quad << 2);
          int n = n0 + nt * 16 + c;
          int b = m >> 12, s = m & 4095, hh = n >> 6, dk = n & 63;
          unsigned short* dst = &oh[(size_t)z * (Bn * Hn * Sn * DKn) +
                                    ((size_t)(b * Hn + hh) * Sn + s) * DKn + dk];
          unsigned pk0 = cvtpk_bf16(acc[mt][nt][0], acc[mt][nt][1]);
          unsigned pk1 = cvtpk_bf16(acc[mt][nt][2], acc[mt][nt][3]);
          dst[0] = (unsigned short)pk0;
          dst[DKn] = (unsigned short)(pk0 >> 16);
          dst[2 * DKn] = (unsigned short)pk1;
          dst[3 * DKn] = (unsigned short)(pk1 >> 16);
        }
    }
  } else {
#pragma unroll
    for (int mt = 0; mt < MT; ++mt)
#pragma unroll
      for (int nt = 0; nt < 8; ++nt)
#pragma unroll
        for (int r = 0; r < 4; ++r) {
          int m = m0 + w * (MT * 16) + mt * 16 + (quad << 2) + r;
          int n = n0 + nt * 16 + c;
          olin[(size_t)m * 512 + n] = acc[mt][nt][r];
        }
  }
}

// ------------------------------------------------------------- flash attn
// 512 thr = 2 kv-groups x 4 waves x 32 q. Static-max softmax; P in regs;
// row-sum l via MFMA ones-trick (lane-local, no shuffles); PV f16 K=32.
// Mask applied as AND on packed f16 P via conflict-free 16-entry LDS table.
// Grid flattened; h = bid&7 so each head's K/V pins to one XCD's L2 (T1).
// NOTE (R2/R3 lessons): prefetch MUST be issued immediately post-barrier
// (late issue exposes HBM latency at the dbuf write: 91->131 us), and NO
// s_setprio here — its scheduler fences force the prefetch regs live across
// the MFMA regions -> per-iteration scratch spill storm (WRITE 16->525 MB,
// 222 us). setprio is fine in gemm_k, fatal here.
__global__ __launch_bounds__(512, 4) void flash_k(
    const unsigned short* __restrict__ Qh, const unsigned short* __restrict__ Kh,
    const unsigned short* __restrict__ VtG, const unsigned int* __restrict__ pmt,
    unsigned short* __restrict__ attn) {
  __shared__ unsigned short Ks[2][2][64 * 64];   // [group][parity][kv][d]
  __shared__ unsigned short Vts[2][2][64 * 64];  // [group][parity][dk][pos]
  __shared__ unsigned int Mw[2][2][256];
  __shared__ unsigned long long MskT[16];        // nibble -> f16x4 AND mask

  const int bid = blockIdx.x;
  const int h = bid & 7;                 // XCD = id%8 -> head h clusters on XCD h
  const int b = (bid >> 3) & 1;
  const int q0 = (bid >> 4) * 128;
  const int t = threadIdx.x;
  const int g = t >> 8, tg = t & 255;
  const int w = (t >> 6) & 3, l = t & 63;
  const int quad = l >> 4, c = l & 15;
  const size_t hb = (size_t)(b * Hn + h) * Sn * DKn;
  const unsigned short* Qg = Qh + hb;

  if (t < 16) {
    unsigned lo = ((t & 1) ? 0xFFFFu : 0u) | ((t & 2) ? 0xFFFF0000u : 0u);
    unsigned hi = ((t & 4) ? 0xFFFFu : 0u) | ((t & 8) ? 0xFFFF0000u : 0u);
    MskT[t] = ((unsigned long long)hi << 32) | lo;
  }

  bf16x8 bQ[2][2];
#pragma unroll
  for (int qf = 0; qf < 2; ++qf) {
    int qrow = q0 + w * 32 + qf * 16 + c;
#pragma unroll
    for (int kc = 0; kc < 2; ++kc)
      bQ[qf][kc] = *(const bf16x8*)&Qg[(size_t)qrow * 64 + kc * 32 + quad * 8];
  }

  f32x4 oacc[2][4] = {};
  f32x4 oaccl[2] = {};                 // rowsum frag: reg r <-> q = quad*4+r
  f16x8 vone8;
#pragma unroll
  for (int i = 0; i < 8; ++i) vone8[i] = (_Float16)1.0f;

  const int sr = tg >> 3, su = tg & 7;
  const int off0 = sr * 64 + ((su ^ (sr & 7)) << 3);
  const int off1 = (sr + 32) * 64 + ((su ^ (sr & 7)) << 3);

  // stepped staging pointers (tile stride: K rows +128, V cols +128, mask +4 rows)
  const unsigned short* kp0 = Kh + hb + ((size_t)(g * 64 + sr)) * 64 + (su << 3);
  const unsigned short* kp1 = kp0 + 32 * 64;
  const unsigned short* vp0 = VtG + hb + (size_t)sr * Sn + g * 64 + (su << 3);
  const unsigned short* vp1 = VtG + hb + (size_t)(sr + 32) * Sn + g * 64 + (su << 3);
  const unsigned int* mp =
      pmt + ((size_t)b * 128 + g * 2 + (tg >> 7)) * 4096 + q0 + (tg & 127);

  us8 kpre[2], vpre[2];
  unsigned mpre;
  kpre[0] = *(const us8*)kp0;
  kpre[1] = *(const us8*)kp1;
  vpre[0] = *(const us8*)vp0;
  vpre[1] = *(const us8*)vp1;
  mpre = *mp;
  *(us8*)&Ks[g][0][off0] = kpre[0];
  *(us8*)&Ks[g][0][off1] = kpre[1];
  *(us8*)&Vts[g][0][off0] = vpre[0];
  *(us8*)&Vts[g][0][off1] = vpre[1];
  Mw[g][0][tg] = mpre;

  for (int it = 0; it < 32; ++it) {
    const int cur = it & 1;
    __syncthreads();
    const bool nxt = it + 1 < 32;
    if (nxt) {
      kp0 += 8192; kp1 += 8192; vp0 += 128; vp1 += 128; mp += 16384;
      kpre[0] = *(const us8*)kp0;
      kpre[1] = *(const us8*)kp1;
      vpre[0] = *(const us8*)vp0;
      vpre[1] = *(const us8*)vp1;
      mpre = *mp;
    }

    // ---- S^T = K . Q^T
    f32x4 sacc[2][4] = {};
#pragma unroll
    for (int kc = 0; kc < 2; ++kc) {
      int u = kc * 4 + quad;
#pragma unroll
      for (int kvt = 0; kvt < 4; ++kvt) {
        int row = kvt * 16 + c;
        bf16x8 aK = *(const bf16x8*)&Ks[g][cur][row * 64 + ((u ^ (c & 7)) << 3)];
#pragma unroll
        for (int qf = 0; qf < 2; ++qf)
          sacc[qf][kvt] = __builtin_amdgcn_mfma_f32_16x16x32_bf16(
              aK, bQ[qf][kc], sacc[qf][kvt], 0, 0, 0);
      }
    }

    // ---- unconditional exp2 -> packed f16, mask via LDS AND-table
    f16x8 ph[2][2];   // [qf][half-of-64kv]
#pragma unroll
    for (int qf = 0; qf < 2; ++qf) {
      int qloc = w * 32 + qf * 16 + c;
      unsigned mv0 = Mw[g][cur][qloc] >> (quad << 2);
      unsigned mv1 = Mw[g][cur][128 + qloc] >> (quad << 2);
#pragma unroll
      for (int half = 0; half < 2; ++half) {
        unsigned wd = half ? mv1 : mv0;
        uint4 ww;
#pragma unroll
        for (int kvh = 0; kvh < 2; ++kvh) {
          const f32x4 s4 = sacc[qf][half * 2 + kvh];
          unsigned long long mk = MskT[(wd >> (kvh << 4)) & 15u];
          unsigned a = __builtin_bit_cast(
              unsigned, __builtin_amdgcn_cvt_pkrtz(
                            __builtin_amdgcn_exp2f(s4[0]),
                            __builtin_amdgcn_exp2f(s4[1])));
          unsigned bpk = __builtin_bit_cast(
              unsigned, __builtin_amdgcn_cvt_pkrtz(
                            __builtin_amdgcn_exp2f(s4[2]),
                            __builtin_amdgcn_exp2f(s4[3])));
          (&ww.x)[kvh * 2] = a & (unsigned)mk;
          (&ww.x)[kvh * 2 + 1] = bpk & (unsigned)(mk >> 32);
        }
        ph[qf][half] = __builtin_bit_cast(f16x8, ww);
      }
    }

    // ---- O += P.V ; l += P.1 (ones-MFMA)
#pragma unroll
    for (int half = 0; half < 2; ++half) {
      int u2 = half * 4 + quad;
#pragma unroll
      for (int dkt = 0; dkt < 4; ++dkt) {
        int dk = dkt * 16 + c;
        f16x8 bV = __builtin_bit_cast(
            f16x8, *(const us8*)&Vts[g][cur][dk * 64 + ((u2 ^ (c & 7)) << 3)]);
#pragma unroll
        for (int qf = 0; qf < 2; ++qf)
          oacc[qf][dkt] = __builtin_amdgcn_mfma_f32_16x16x32_f16(
              ph[qf][half], bV, oacc[qf][dkt], 0, 0, 0);
      }
#pragma unroll
      for (int qf = 0; qf < 2; ++qf)
        oaccl[qf] = __builtin_amdgcn_mfma_f32_16x16x32_f16(
            ph[qf][half], vone8, oaccl[qf], 0, 0, 0);
    }

    if (nxt) {
      const int nb = cur ^ 1;
      *(us8*)&Ks[g][nb][off0] = kpre[0];
      *(us8*)&Ks[g][nb][off1] = kpre[1];
      *(us8*)&Vts[g][nb][off0] = vpre[0];
      *(us8*)&Vts[g][nb][off1] = vpre[1];
      Mw[g][nb][tg] = mpre;
    }
  }

  // ---- combine groups (plain sums), normalize, store (group 0)
  __syncthreads();
  float* fsum = (float*)&Ks[0][0][0];          // [qf][dkt][w][l] f32x4 = 32 KB
  float* flsum = (float*)&Vts[0][0][0];        // [qf][w][l] f32x4 = 8 KB
  if (g == 1) {
#pragma unroll
    for (int qf = 0; qf < 2; ++qf) {
#pragma unroll
      for (int dkt = 0; dkt < 4; ++dkt)
        *(f32x4*)&fsum[(((qf * 4 + dkt) * 4 + w) * 64 + l) * 4] = oacc[qf][dkt];
      *(f32x4*)&flsum[((qf * 4 + w) * 64 + l) * 4] = oaccl[qf];
    }
  }
  __syncthreads();
  if (g == 0) {
#pragma unroll
    for (int qf = 0; qf < 2; ++qf) {
      f32x4 l1 = *(const f32x4*)&flsum[((qf * 4 + w) * 64 + l) * 4];
#pragma unroll
      for (int r = 0; r < 4; ++r) oaccl[qf][r] += l1[r];
#pragma unroll
      for (int dkt = 0; dkt < 4; ++dkt) {
        f32x4 o1 = *(const f32x4*)&fsum[(((qf * 4 + dkt) * 4 + w) * 64 + l) * 4];
#pragma unroll
        for (int r = 0; r < 4; ++r) oacc[qf][dkt][r] += o1[r];
      }
    }
#pragma unroll
    for (int qf = 0; qf < 2; ++qf)
#pragma unroll
      for (int r = 0; r < 4; ++r) {
        float invr = 1.0f / oaccl[qf][r];
        unsigned short* dst =
            &attn[((size_t)(b * Sn + q0 + w * 32 + qf * 16 + (quad << 2) + r)) * Dn +
                  h * 64 + c];
#pragma unroll
        for (int dkt = 0; dkt < 4; ++dkt)
          dst[dkt * 16] = f2bf(oacc[qf][dkt][r] * invr);
      }
  }
}

// ------------------------------------------------------------------ launch
extern "C" void kernel_launch(void* const* d_in, const int* in_sizes, int n_in,
                              void* d_out, int out_size, void* d_ws,
                              size_t ws_size, hipStream_t stream) {
  const float* q = (const float*)d_in[0];
  const float* k = (const float*)d_in[1];
  const float* v = (const float*)d_in[2];
  const int* mask = (const int*)d_in[3];
  const float* wq = (const float*)d_in[4];
  const float* wk = (const float*)d_in[5];
  const float* wv = (const float*)d_in[6];
  const float* wo = (const float*)d_in[7];
  float* out = (float*)d_out;

  char* ws = (char*)d_ws;
  const size_t headN = (size_t)Bn * Hn * Sn * DKn;        // 4,194,304 elems
  const size_t tensB = headN * 2;                          // 8 MB
  unsigned short* attn = (unsigned short*)ws;
  size_t off = 3 * tensB;
  unsigned short* qkv = (unsigned short*)(ws + off);       // Q,K heads + V^T
  off += 3 * tensB;
  unsigned short* wt = (unsigned short*)(ws + off);        // 2 MB
  off += 4ull * 512 * 512 * 2;
  unsigned int* pm = (unsigned int*)(ws + off);            // 4 MB transposed

  prep_k<<<4352, 256, 0, stream>>>(mask, pm, wq, wk, wv, wo, wt);
  gemm_k<2, true><<<dim3(64, 4, 3), 256, 0, stream>>>(
      q, k, v, nullptr, wt, qkv, qkv + 2 * headN, nullptr);
  flash_k<<<dim3(512), 512, 0, stream>>>(qkv, qkv + headN,
                                         qkv + 2 * headN, pm, attn);
  gemm_k<1, false><<<dim3(128, 4, 1), 256, 0, stream>>>(
      nullptr, nullptr, nullptr, attn, wt + 3ull * 512 * 512, nullptr, nullptr,
      out);
}